// Round 11
// baseline (67.290 us; speedup 1.0000x reference)
//
#include <hip/hip_runtime.h>

#define HW 16384
#define CIN 64
#define COUT 64
#define HH 128
#define WW 128
#define NB 4
#define PXB 16

typedef __attribute__((ext_vector_type(8))) short bf16x8;
typedef __attribute__((ext_vector_type(4))) float f32x4;
typedef __attribute__((ext_vector_type(2))) unsigned u32x2;

__device__ __forceinline__ unsigned short f32_bf16(float f) {
  unsigned u = __builtin_bit_cast(unsigned, f);
  u += 0x7fffu + ((u >> 16) & 1u);
  return (unsigned short)(u >> 16);
}
__device__ __forceinline__ float bits_f32(unsigned u) {
  return __builtin_bit_cast(float, u);
}
// order-pinned 8B global load (forces all gathers to issue before any wait)
__device__ __forceinline__ u32x2 gload8(const unsigned short* p) {
  u32x2 r;
  unsigned long long a = (unsigned long long)p;
  asm volatile("global_load_dwordx2 %0, %1, off" : "=v"(r) : "v"(a));
  return r;
}

// ---- fused prep: blocks [0,1024) transpose x; [1024,1168) transpose w ----
// x: [N][C][HW] -> bf16 [N][HW][C];  w: [o][c][k] -> bf16 [o][k*64+c]
__global__ __launch_bounds__(256) void prep_kernel(
    const float* __restrict__ x, const float* __restrict__ w,
    unsigned short* __restrict__ xt, unsigned short* __restrict__ wt) {
  __shared__ float tile[64][65];
  const int bid = blockIdx.x;
  if (bid < 1024) {
    const int n = bid >> 8;
    const int hw0 = (bid & 255) * 64;
    const int tx = threadIdx.x & 63;
    const int ty = threadIdx.x >> 6;
    const float* xp = x + (size_t)n * CIN * HW;
    #pragma unroll
    for (int c = ty; c < 64; c += 4)
      tile[c][tx] = xp[(size_t)c * HW + hw0 + tx];
    __syncthreads();
    unsigned short* xtp = xt + (size_t)n * HW * CIN;
    #pragma unroll
    for (int hw = ty; hw < 64; hw += 4)
      xtp[(size_t)(hw0 + hw) * CIN + tx] = f32_bf16(tile[tx][hw]);
  } else {
    const int i = (bid - 1024) * 256 + threadIdx.x;
    if (i < 64 * 576) {
      const int o = i / 576;
      const int t = i % 576;          // t = k*64 + c
      const int c = t & 63;
      const int k = t >> 6;
      wt[i] = f32_bf16(w[((size_t)o * 64 + c) * 9 + k]);
    }
  }
}

// ---- main: param-precompute -> batched asm gather -> MFMA -> store ------
// block = 256 thr = 4 waves = 16 pixels.
// Phase 0: threads 0..143 compute per-(px,tap) bilinear weights + packed
//   clamped corner indices into LDS (kills 16x-redundant per-lane math).
// Phase 1: group g owns px=wave*4+g; lane li covers ch li*4..+3. Params ->
//   regs, then ALL 36 corner loads issued via order-pinned asm, one
//   vmcnt(0) drain, sched_barrier, then blend+cvt_pk+ds_write.
// Phase 2: C[16 px][64 oc] = S[16][576] * W^T; 18 MFMA/wave; f32x4 store.
__global__ __launch_bounds__(256, 2) void deform_mfma(
    const unsigned short* __restrict__ xt, const float* __restrict__ offset,
    const unsigned short* __restrict__ wt, float* __restrict__ out) {
  __shared__ unsigned short s[PXB][584];   // 1168 B row stride
  __shared__ f32x4 pw[144];                // bilinear weights per (tap,px)
  __shared__ uint2 pidx[144];              // packed corner indices
  const int tid = threadIdx.x;
  const int wave = tid >> 6;
  const int lane = tid & 63;
  const int g = lane >> 4;
  const int li = lane & 15;
  const int p0 = blockIdx.x * PXB;
  const int n = p0 >> 14;
  const int rem0 = p0 & 16383;

  // ---- phase 0: per-(px,tap) params ----
  if (tid < 144) {
    const int px = tid & 15;
    const int tap = tid >> 4;
    const int rem = rem0 + px;
    const int y = rem >> 7;
    const int x = rem & 127;
    const float* offb = offset + (size_t)n * 18 * HW + rem;
    const float dy = offb[(size_t)(2 * tap) * HW];
    const float dx = offb[(size_t)(2 * tap + 1) * HW];
    const float fy = floorf(dy);
    const float fx = floorf(dx);
    const float ly = dy - fy;
    const float lx = dx - fx;
    const int y0 = y - 1 + (tap / 3) + (int)fy;
    const int x0 = x - 1 + (tap % 3) + (int)fx;
    const int y1 = y0 + 1, x1 = x0 + 1;
    const bool vy0 = (unsigned)y0 < (unsigned)HH;
    const bool vy1 = (unsigned)y1 < (unsigned)HH;
    const bool vx0 = (unsigned)x0 < (unsigned)WW;
    const bool vx1 = (unsigned)x1 < (unsigned)WW;
    const int cy0 = min(max(y0, 0), HH - 1);
    const int cy1 = min(max(y1, 0), HH - 1);
    const int cx0 = min(max(x0, 0), WW - 1);
    const int cx1 = min(max(x1, 0), WW - 1);
    const float omly = 1.f - ly, omlx = 1.f - lx;
    f32x4 w4;
    w4[0] = (vy0 && vx0) ? omly * omlx : 0.f;
    w4[1] = (vy0 && vx1) ? omly * lx : 0.f;
    w4[2] = (vy1 && vx0) ? ly * omlx : 0.f;
    w4[3] = (vy1 && vx1) ? ly * lx : 0.f;
    const unsigned i00 = (unsigned)(cy0 * WW + cx0);
    const unsigned i01 = (unsigned)(cy0 * WW + cx1);
    const unsigned i10 = (unsigned)(cy1 * WW + cx0);
    const unsigned i11 = (unsigned)(cy1 * WW + cx1);
    pw[tid] = w4;
    pidx[tid] = make_uint2(i00 | (i01 << 16), i10 | (i11 << 16));
  }
  __syncthreads();

  // ---- phase 1: batched gather + blend ----
  const int px = wave * 4 + g;
  const unsigned short* xli = xt + (size_t)n * HW * CIN + li * 4;

  f32x4 w4[9];
  uint2 id[9];
  #pragma unroll
  for (int k = 0; k < 9; ++k) {
    w4[k] = pw[k * 16 + px];
    id[k] = pidx[k * 16 + px];
  }
  u32x2 V00[9], V01[9], V10[9], V11[9];
  #pragma unroll
  for (int k = 0; k < 9; ++k) {
    V00[k] = gload8(xli + (size_t)(id[k].x & 0xffffu) * CIN);
    V01[k] = gload8(xli + (size_t)(id[k].x >> 16) * CIN);
    V10[k] = gload8(xli + (size_t)(id[k].y & 0xffffu) * CIN);
    V11[k] = gload8(xli + (size_t)(id[k].y >> 16) * CIN);
  }
  asm volatile("s_waitcnt vmcnt(0)" ::: "memory");
  __builtin_amdgcn_sched_barrier(0);   // rule 18: fence reg-only consumers

  #pragma unroll
  for (int k = 0; k < 9; ++k) {
    float a0 = 0.f, a1 = 0.f, a2 = 0.f, a3 = 0.f;
    #define CORNER(v, wc)                                     \
      a0 = fmaf(bits_f32((v)[0] << 16), (wc), a0);            \
      a1 = fmaf(bits_f32((v)[0] & 0xffff0000u), (wc), a1);    \
      a2 = fmaf(bits_f32((v)[1] << 16), (wc), a2);            \
      a3 = fmaf(bits_f32((v)[1] & 0xffff0000u), (wc), a3);
    CORNER(V00[k], w4[k][0]);
    CORNER(V01[k], w4[k][1]);
    CORNER(V10[k], w4[k][2]);
    CORNER(V11[k], w4[k][3]);
    #undef CORNER
    unsigned r01, r23;
    asm("v_cvt_pk_bf16_f32 %0, %1, %2" : "=v"(r01) : "v"(a0), "v"(a1));
    asm("v_cvt_pk_bf16_f32 %0, %1, %2" : "=v"(r23) : "v"(a2), "v"(a3));
    *(uint2*)&s[px][k * 64 + li * 4] = make_uint2(r01, r23);
  }
  __syncthreads();

  // ---- phase 2: MFMA ----
  f32x4 acc = {0.f, 0.f, 0.f, 0.f};
  const unsigned short* ap = &s[li][g * 8];
  const unsigned short* bp = wt + ((size_t)(wave * 16 + li)) * 576 + g * 8;
  #pragma unroll
  for (int t0 = 0; t0 < 576; t0 += 32) {
    bf16x8 av = *(const bf16x8*)(ap + t0);
    bf16x8 bv = *(const bf16x8*)(bp + t0);
    acc = __builtin_amdgcn_mfma_f32_16x16x32_bf16(av, bv, acc, 0, 0, 0);
  }

  const int oc = wave * 16 + li;
  float* ob = out + ((size_t)n * COUT + oc) * HW + rem0 + g * 4;
  *(f32x4*)ob = acc;
}

// ---------------- fp32 fallback (ws too small) --------------------------
__global__ __launch_bounds__(256) void deform_fallback(
    const float* __restrict__ xsrc, const float* __restrict__ offset,
    const float* __restrict__ wsrc, float* __restrict__ out) {
  __shared__ float s[16][576];
  const int wave = threadIdx.x >> 6;
  const int lane = threadIdx.x & 63;
  const int p0 = blockIdx.x * 16;
  for (int i = 0; i < 4; ++i) {
    const int p = p0 + wave * 4 + i;
    const int n = p >> 14;
    const int rem = p & 16383;
    const int y = rem >> 7;
    const int x = rem & 127;
    const float* off = offset + (size_t)n * 18 * HW + rem;
    const float* xb = xsrc + (size_t)n * CIN * HW;
    #pragma unroll
    for (int k = 0; k < 9; ++k) {
      const float dy = off[(size_t)(2 * k) * HW];
      const float dx = off[(size_t)(2 * k + 1) * HW];
      const float py = (float)(y - 1 + k / 3) + dy;
      const float px = (float)(x - 1 + k % 3) + dx;
      const float y0f = floorf(py), x0f = floorf(px);
      const float ly = py - y0f, lx = px - x0f;
      const int y0 = (int)y0f, x0 = (int)x0f;
      const int y1 = y0 + 1, x1 = x0 + 1;
      const bool vy0 = (y0 >= 0) && (y0 < HH), vy1 = (y1 >= 0) && (y1 < HH);
      const bool vx0 = (x0 >= 0) && (x0 < WW), vx1 = (x1 >= 0) && (x1 < WW);
      const int cy0 = min(max(y0, 0), HH - 1), cy1 = min(max(y1, 0), HH - 1);
      const int cx0 = min(max(x0, 0), WW - 1), cx1 = min(max(x1, 0), WW - 1);
      const float v00 = (vy0 && vx0) ? xb[(size_t)lane * HW + cy0 * WW + cx0] : 0.f;
      const float v01 = (vy0 && vx1) ? xb[(size_t)lane * HW + cy0 * WW + cx1] : 0.f;
      const float v10 = (vy1 && vx0) ? xb[(size_t)lane * HW + cy1 * WW + cx0] : 0.f;
      const float v11 = (vy1 && vx1) ? xb[(size_t)lane * HW + cy1 * WW + cx1] : 0.f;
      s[wave * 4 + i][k * 64 + lane] =
          v00 * (1.f - ly) * (1.f - lx) + v01 * (1.f - ly) * lx +
          v10 * ly * (1.f - lx) + v11 * ly * lx;
    }
  }
  __syncthreads();
  float a0 = 0.f, a1 = 0.f, a2 = 0.f, a3 = 0.f;
  const int pb = wave * 4;
  for (int t = 0; t < 576; ++t) {
    const int c = t & 63;
    const int k = t >> 6;
    const float wv = wsrc[((size_t)lane * 64 + c) * 9 + k];
    a0 += s[pb + 0][t] * wv;
    a1 += s[pb + 1][t] * wv;
    a2 += s[pb + 2][t] * wv;
    a3 += s[pb + 3][t] * wv;
  }
  const float acc[4] = {a0, a1, a2, a3};
  for (int i = 0; i < 4; ++i) {
    const int p = p0 + pb + i;
    const int n = p >> 14;
    const int rem = p & 16383;
    out[((size_t)n * COUT + lane) * HW + rem] = acc[i];
  }
}

extern "C" void kernel_launch(void* const* d_in, const int* in_sizes, int n_in,
                              void* d_out, int out_size, void* d_ws,
                              size_t ws_size, hipStream_t stream) {
  const float* x = (const float*)d_in[0];
  const float* offset = (const float*)d_in[1];
  const float* weight = (const float*)d_in[2];
  float* out = (float*)d_out;

  const size_t xt_elems = (size_t)NB * HW * CIN;       // bf16
  const size_t wt_elems = (size_t)64 * 576;            // bf16
  const size_t need = (xt_elems + wt_elems) * sizeof(short);

  if (ws_size >= need) {
    unsigned short* xtp = (unsigned short*)d_ws;
    unsigned short* wtp = xtp + xt_elems;
    prep_kernel<<<1024 + 144, 256, 0, stream>>>(x, weight, xtp, wtp);
    deform_mfma<<<NB * HW / PXB, 256, 0, stream>>>(xtp, offset, wtp, out);
  } else {
    deform_fallback<<<NB * HW / 16, 256, 0, stream>>>(x, offset, weight, out);
  }
}

// Round 12
// 51.358 us; speedup vs baseline: 1.3102x; 1.3102x over previous
//
#include <hip/hip_runtime.h>

#define HW 16384
#define CIN 64
#define COUT 64
#define HH 128
#define WW 128
#define NB 4
#define PXB 32
#define TPB 4

typedef __attribute__((ext_vector_type(8))) short bf16x8;
typedef __attribute__((ext_vector_type(4))) float f32x4;
typedef __attribute__((ext_vector_type(4))) unsigned short u16x4;

__device__ __forceinline__ unsigned short f32_bf16(float f) {
  unsigned u = __builtin_bit_cast(unsigned, f);
  u += 0x7fffu + ((u >> 16) & 1u);
  return (unsigned short)(u >> 16);
}
__device__ __forceinline__ float bits_f32(unsigned u) {
  return __builtin_bit_cast(float, u);
}

// ---- fused prep: blocks [0,1024) transpose x; [1024,1168) transpose w ----
// x: [N][C][HW] -> bf16 [N][HW][C];  w: [o][c][k] -> bf16 [o][k*64+c]
__global__ __launch_bounds__(256) void prep_kernel(
    const float* __restrict__ x, const float* __restrict__ w,
    unsigned short* __restrict__ xt, unsigned short* __restrict__ wt) {
  __shared__ float tile[64][65];
  const int bid = blockIdx.x;
  if (bid < 1024) {
    const int n = bid >> 8;
    const int hw0 = (bid & 255) * 64;
    const int tx = threadIdx.x & 63;
    const int ty = threadIdx.x >> 6;
    const float* xp = x + (size_t)n * CIN * HW;
    #pragma unroll
    for (int c = ty; c < 64; c += 4)
      tile[c][tx] = xp[(size_t)c * HW + hw0 + tx];
    __syncthreads();
    unsigned short* xtp = xt + (size_t)n * HW * CIN;
    #pragma unroll
    for (int hw = ty; hw < 64; hw += 4)
      xtp[(size_t)(hw0 + hw) * CIN + tx] = f32_bf16(tile[tx][hw]);
  } else {
    const int i = (bid - 1024) * 256 + threadIdx.x;
    if (i < 64 * 576) {
      const int o = i / 576;
      const int t = i % 576;          // t = k*64 + c
      const int c = t & 63;
      const int k = t >> 6;
      wt[i] = f32_bf16(w[((size_t)o * 64 + c) * 9 + k]);
    }
  }
}

// ---- main: tile-looped {params -> gather -> MFMA} with offset prefetch --
// block = 256 thr = 4 waves; TPB tiles of PXB=32 px each (128 px/block).
// Per tile:
//   phase0: thread i computes params for (tap=i>>5, px=i&31) from
//           PREFETCHED offset regs -> pw/pidx in LDS. (tid<32 also tap=8.)
//   BAR; prefetch next tile's offsets (in flight during gather+MFMA);
//   phase1: 2 rounds, lane-group g owns px=wave*8+r*4+g; lane li covers
//           ch li*4..+3; 36 corner loads batched (R7-style), blend, cvt_pk.
//   BAR; phase2: C[32px][64oc], wave w -> oc w*16..+15, 2 A-tiles share
//           each B-frag, 18 K-steps, direct f32x4 stores.
__global__ __launch_bounds__(256, 2) void deform_mfma(
    const unsigned short* __restrict__ xt, const float* __restrict__ offset,
    const unsigned short* __restrict__ wt, float* __restrict__ out) {
  __shared__ unsigned short s[PXB][584];   // 37.4 KB sampled tile
  __shared__ f32x4 pw[288];                // bilinear weights per (tap,px)
  __shared__ uint2 pidx[288];              // packed corner indices
  const int tid = threadIdx.x;
  const int wave = tid >> 6;
  const int lane = tid & 63;
  const int g = lane >> 4;
  const int li = lane & 15;
  const int base = blockIdx.x * (PXB * TPB);
  const int n = base >> 14;                // 128 px per block, no n straddle
  const int rem_base = base & 16383;

  const float* offb = offset + (size_t)n * 18 * HW;
  const unsigned short* xli = xt + (size_t)n * HW * CIN + li * 4;

  const int px0 = tid & 31;
  const int tap0 = tid >> 5;

  // prologue: prefetch tile-0 offsets
  float dy0, dx0, dy1 = 0.f, dx1 = 0.f;
  {
    const int rem = rem_base + px0;
    dy0 = offb[(size_t)(2 * tap0) * HW + rem];
    dx0 = offb[(size_t)(2 * tap0 + 1) * HW + rem];
    if (tid < 32) {
      dy1 = offb[(size_t)16 * HW + rem];
      dx1 = offb[(size_t)17 * HW + rem];
    }
  }

  #pragma unroll 1
  for (int t = 0; t < TPB; ++t) {
    const int rem0 = rem_base + t * PXB;

    // ---- phase 0: params from prefetched regs ----
    {
      const int rem = rem0 + px0;
      const int y = rem >> 7;
      const int x = rem & 127;
      #pragma unroll
      for (int item = 0; item < 2; ++item) {
        if (item == 1 && tid >= 32) break;
        const int tap = item ? 8 : tap0;
        const float dy = item ? dy1 : dy0;
        const float dx = item ? dx1 : dx0;
        const float fy = floorf(dy);
        const float fx = floorf(dx);
        const float ly = dy - fy;
        const float lx = dx - fx;
        const int y0 = y - 1 + (tap / 3) + (int)fy;
        const int x0 = x - 1 + (tap % 3) + (int)fx;
        const int y1 = y0 + 1, x1 = x0 + 1;
        const bool vy0 = (unsigned)y0 < (unsigned)HH;
        const bool vy1 = (unsigned)y1 < (unsigned)HH;
        const bool vx0 = (unsigned)x0 < (unsigned)WW;
        const bool vx1 = (unsigned)x1 < (unsigned)WW;
        const int cy0 = min(max(y0, 0), HH - 1);
        const int cy1 = min(max(y1, 0), HH - 1);
        const int cx0 = min(max(x0, 0), WW - 1);
        const int cx1 = min(max(x1, 0), WW - 1);
        const float omly = 1.f - ly, omlx = 1.f - lx;
        f32x4 w4;
        w4[0] = (vy0 && vx0) ? omly * omlx : 0.f;
        w4[1] = (vy0 && vx1) ? omly * lx : 0.f;
        w4[2] = (vy1 && vx0) ? ly * omlx : 0.f;
        w4[3] = (vy1 && vx1) ? ly * lx : 0.f;
        const unsigned i00 = (unsigned)(cy0 * WW + cx0);
        const unsigned i01 = (unsigned)(cy0 * WW + cx1);
        const unsigned i10 = (unsigned)(cy1 * WW + cx0);
        const unsigned i11 = (unsigned)(cy1 * WW + cx1);
        const int slot = tap * 32 + px0;
        pw[slot] = w4;
        pidx[slot] = make_uint2(i00 | (i01 << 16), i10 | (i11 << 16));
      }
    }
    __syncthreads();

    // ---- prefetch next tile's offsets (hidden under gather + MFMA) ----
    if (t + 1 < TPB) {
      const int rem = rem0 + PXB + px0;
      dy0 = offb[(size_t)(2 * tap0) * HW + rem];
      dx0 = offb[(size_t)(2 * tap0 + 1) * HW + rem];
      if (tid < 32) {
        dy1 = offb[(size_t)16 * HW + rem];
        dx1 = offb[(size_t)17 * HW + rem];
      }
    }

    // ---- phase 1: batched gather + blend (R7 structure) ----
    #pragma unroll 1
    for (int r = 0; r < 2; ++r) {
      const int px = wave * 8 + r * 4 + g;
      f32x4 w4[9];
      uint2 id[9];
      #pragma unroll
      for (int k = 0; k < 9; ++k) {
        w4[k] = pw[k * 32 + px];
        id[k] = pidx[k * 32 + px];
      }
      u16x4 V00[9], V01[9], V10[9], V11[9];
      #pragma unroll
      for (int k = 0; k < 9; ++k) {
        V00[k] = *(const u16x4*)(xli + (size_t)(id[k].x & 0xffffu) * CIN);
        V01[k] = *(const u16x4*)(xli + (size_t)(id[k].x >> 16) * CIN);
        V10[k] = *(const u16x4*)(xli + (size_t)(id[k].y & 0xffffu) * CIN);
        V11[k] = *(const u16x4*)(xli + (size_t)(id[k].y >> 16) * CIN);
      }
      __builtin_amdgcn_sched_barrier(0);   // keep the 36 loads batched
      #pragma unroll
      for (int k = 0; k < 9; ++k) {
        float a0 = 0.f, a1 = 0.f, a2 = 0.f, a3 = 0.f;
        #pragma unroll
        for (int c = 0; c < 4; ++c) {
          const f32x4* wp = &w4[k];
          (void)wp;
        }
        #define CORNER(v, wc)                                  \
          a0 = fmaf(bits_f32((unsigned)(v)[0] << 16), (wc), a0); \
          a1 = fmaf(bits_f32(((unsigned)(v)[1]) << 16), (wc), a1); \
          a2 = fmaf(bits_f32((unsigned)(v)[2] << 16), (wc), a2); \
          a3 = fmaf(bits_f32(((unsigned)(v)[3]) << 16), (wc), a3);
        CORNER(V00[k], w4[k][0]);
        CORNER(V01[k], w4[k][1]);
        CORNER(V10[k], w4[k][2]);
        CORNER(V11[k], w4[k][3]);
        #undef CORNER
        unsigned r01, r23;
        asm("v_cvt_pk_bf16_f32 %0, %1, %2" : "=v"(r01) : "v"(a0), "v"(a1));
        asm("v_cvt_pk_bf16_f32 %0, %1, %2" : "=v"(r23) : "v"(a2), "v"(a3));
        *(uint2*)&s[px][k * 64 + li * 4] = make_uint2(r01, r23);
      }
      __builtin_amdgcn_sched_barrier(0);
    }
    __syncthreads();

    // ---- phase 2: MFMA, one oc-tile per wave, two pixel tiles ----
    f32x4 acc0 = {0.f, 0.f, 0.f, 0.f};
    f32x4 acc1 = {0.f, 0.f, 0.f, 0.f};
    const unsigned short* ap0 = &s[li][g * 8];
    const unsigned short* ap1 = &s[16 + li][g * 8];
    const unsigned short* bp = wt + ((size_t)(wave * 16 + li)) * 576 + g * 8;
    #pragma unroll
    for (int t0 = 0; t0 < 576; t0 += 32) {
      bf16x8 bv = *(const bf16x8*)(bp + t0);
      bf16x8 a0 = *(const bf16x8*)(ap0 + t0);
      bf16x8 a1 = *(const bf16x8*)(ap1 + t0);
      acc0 = __builtin_amdgcn_mfma_f32_16x16x32_bf16(a0, bv, acc0, 0, 0, 0);
      acc1 = __builtin_amdgcn_mfma_f32_16x16x32_bf16(a1, bv, acc1, 0, 0, 0);
    }

    const int oc = wave * 16 + li;
    float* ob = out + ((size_t)n * COUT + oc) * HW + rem0 + g * 4;
    *(f32x4*)ob = acc0;
    *(f32x4*)(ob + 16) = acc1;
    // no barrier needed here: next tile's phase0 touches only pw/pidx
    // (not read in phase2); s is overwritten only after the phase0 barrier.
  }
}

// ---------------- fp32 fallback (ws too small) --------------------------
__global__ __launch_bounds__(256) void deform_fallback(
    const float* __restrict__ xsrc, const float* __restrict__ offset,
    const float* __restrict__ wsrc, float* __restrict__ out) {
  __shared__ float s[16][576];
  const int wave = threadIdx.x >> 6;
  const int lane = threadIdx.x & 63;
  const int p0 = blockIdx.x * 16;
  for (int i = 0; i < 4; ++i) {
    const int p = p0 + wave * 4 + i;
    const int n = p >> 14;
    const int rem = p & 16383;
    const int y = rem >> 7;
    const int x = rem & 127;
    const float* off = offset + (size_t)n * 18 * HW + rem;
    const float* xb = xsrc + (size_t)n * CIN * HW;
    #pragma unroll
    for (int k = 0; k < 9; ++k) {
      const float dy = off[(size_t)(2 * k) * HW];
      const float dx = off[(size_t)(2 * k + 1) * HW];
      const float py = (float)(y - 1 + k / 3) + dy;
      const float px = (float)(x - 1 + k % 3) + dx;
      const float y0f = floorf(py), x0f = floorf(px);
      const float ly = py - y0f, lx = px - x0f;
      const int y0 = (int)y0f, x0 = (int)x0f;
      const int y1 = y0 + 1, x1 = x0 + 1;
      const bool vy0 = (y0 >= 0) && (y0 < HH), vy1 = (y1 >= 0) && (y1 < HH);
      const bool vx0 = (x0 >= 0) && (x0 < WW), vx1 = (x1 >= 0) && (x1 < WW);
      const int cy0 = min(max(y0, 0), HH - 1), cy1 = min(max(y1, 0), HH - 1);
      const int cx0 = min(max(x0, 0), WW - 1), cx1 = min(max(x1, 0), WW - 1);
      const float v00 = (vy0 && vx0) ? xb[(size_t)lane * HW + cy0 * WW + cx0] : 0.f;
      const float v01 = (vy0 && vx1) ? xb[(size_t)lane * HW + cy0 * WW + cx1] : 0.f;
      const float v10 = (vy1 && vx0) ? xb[(size_t)lane * HW + cy1 * WW + cx0] : 0.f;
      const float v11 = (vy1 && vx1) ? xb[(size_t)lane * HW + cy1 * WW + cx1] : 0.f;
      s[wave * 4 + i][k * 64 + lane] =
          v00 * (1.f - ly) * (1.f - lx) + v01 * (1.f - ly) * lx +
          v10 * ly * (1.f - lx) + v11 * ly * lx;
    }
  }
  __syncthreads();
  float a0 = 0.f, a1 = 0.f, a2 = 0.f, a3 = 0.f;
  const int pb = wave * 4;
  for (int t = 0; t < 576; ++t) {
    const int c = t & 63;
    const int k = t >> 6;
    const float wv = wsrc[((size_t)lane * 64 + c) * 9 + k];
    a0 += s[pb + 0][t] * wv;
    a1 += s[pb + 1][t] * wv;
    a2 += s[pb + 2][t] * wv;
    a3 += s[pb + 3][t] * wv;
  }
  const float acc[4] = {a0, a1, a2, a3};
  for (int i = 0; i < 4; ++i) {
    const int p = p0 + pb + i;
    const int n = p >> 14;
    const int rem = p & 16383;
    out[((size_t)n * COUT + lane) * HW + rem] = acc[i];
  }
}

extern "C" void kernel_launch(void* const* d_in, const int* in_sizes, int n_in,
                              void* d_out, int out_size, void* d_ws,
                              size_t ws_size, hipStream_t stream) {
  const float* x = (const float*)d_in[0];
  const float* offset = (const float*)d_in[1];
  const float* weight = (const float*)d_in[2];
  float* out = (float*)d_out;

  const size_t xt_elems = (size_t)NB * HW * CIN;       // bf16
  const size_t wt_elems = (size_t)64 * 576;            // bf16
  const size_t need = (xt_elems + wt_elems) * sizeof(short);

  if (ws_size >= need) {
    unsigned short* xtp = (unsigned short*)d_ws;
    unsigned short* wtp = xtp + xt_elems;
    prep_kernel<<<1024 + 144, 256, 0, stream>>>(x, weight, xtp, wtp);
    deform_mfma<<<NB * HW / (PXB * TPB), 256, 0, stream>>>(xtp, offset, wtp, out);
  } else {
    deform_fallback<<<NB * HW / 16, 256, 0, stream>>>(x, offset, weight, out);
  }
}

// Round 13
// 44.738 us; speedup vs baseline: 1.5041x; 1.1480x over previous
//
#include <hip/hip_runtime.h>

#define HW 16384
#define CIN 64
#define COUT 64
#define HH 128
#define WW 128
#define NB 4
#define PXB 16
#define TPB 8

typedef __attribute__((ext_vector_type(8))) short bf16x8;
typedef __attribute__((ext_vector_type(4))) float f32x4;
typedef __attribute__((ext_vector_type(4))) unsigned short u16x4;

__device__ __forceinline__ unsigned short f32_bf16(float f) {
  unsigned u = __builtin_bit_cast(unsigned, f);
  u += 0x7fffu + ((u >> 16) & 1u);
  return (unsigned short)(u >> 16);
}
__device__ __forceinline__ float bits_f32(unsigned u) {
  return __builtin_bit_cast(float, u);
}

// ---- fused prep: blocks [0,1024) transpose x; [1024,1168) transpose w ----
// x: [N][C][HW] -> bf16 [N][HW][C];  w: [o][c][k] -> bf16 [o][k*64+c]
__global__ __launch_bounds__(256) void prep_kernel(
    const float* __restrict__ x, const float* __restrict__ w,
    unsigned short* __restrict__ xt, unsigned short* __restrict__ wt) {
  __shared__ float tile[64][65];
  const int bid = blockIdx.x;
  if (bid < 1024) {
    const int n = bid >> 8;
    const int hw0 = (bid & 255) * 64;
    const int tx = threadIdx.x & 63;
    const int ty = threadIdx.x >> 6;
    const float* xp = x + (size_t)n * CIN * HW;
    #pragma unroll
    for (int c = ty; c < 64; c += 4)
      tile[c][tx] = xp[(size_t)c * HW + hw0 + tx];
    __syncthreads();
    unsigned short* xtp = xt + (size_t)n * HW * CIN;
    #pragma unroll
    for (int hw = ty; hw < 64; hw += 4)
      xtp[(size_t)(hw0 + hw) * CIN + tx] = f32_bf16(tile[tx][hw]);
  } else {
    const int i = (bid - 1024) * 256 + threadIdx.x;
    if (i < 64 * 576) {
      const int o = i / 576;
      const int t = i % 576;          // t = k*64 + c
      const int c = t & 63;
      const int k = t >> 6;
      wt[i] = f32_bf16(w[((size_t)o * 64 + c) * 9 + k]);
    }
  }
}

// ---- main: 2-stage pipeline {issue gathers(t) | MFMA(t-1) | blend(t)} ---
// block = 256 thr = 4 waves; TPB=8 tiles of PXB=16 px (128 px/block);
// grid = 512 -> 2 blocks/CU, whole grid co-resident.
// Per tile: A params(t)->pw/pidx[t&1]; B2 bar; C prefetch offsets(t+1);
//   D issue 36 corner gathers (regs); M MFMA(t-1) -- pure LDS+reg (B-frags
//   preloaded per block, so no vmcnt wait drains the gathers); B3 bar;
//   E blend -> s. MFMA hides the gather latency.
__global__ __launch_bounds__(256, 2) void deform_mfma(
    const unsigned short* __restrict__ xt, const float* __restrict__ offset,
    const unsigned short* __restrict__ wt, float* __restrict__ out) {
  __shared__ unsigned short s[PXB][584];   // 18.7 KB sampled tile
  __shared__ f32x4 pw[2][144];             // per-(tap,px) weights, dbuf
  __shared__ uint2 pidx[2][144];           // packed corner indices, dbuf
  const int tid = threadIdx.x;
  const int wave = tid >> 6;
  const int lane = tid & 63;
  const int g = lane >> 4;
  const int li = lane & 15;
  const int base = blockIdx.x * (PXB * TPB);
  const int n = base >> 14;                // 128 px/block, no n straddle
  const int rem_base = base & 16383;

  const float* offb = offset + (size_t)n * 18 * HW;
  const unsigned short* xli = xt + (size_t)n * HW * CIN + li * 4;

  const int px0 = tid & 15;
  const int tap0 = tid >> 4;               // params thread iff tap0 < 9
  const bool pthr = tap0 < 9;

  // B-fragments are tile-invariant: preload once (18 x 4 VGPR, held).
  bf16x8 bv[18];
  {
    const unsigned short* bp = wt + ((size_t)(wave * 16 + li)) * 576 + g * 8;
    #pragma unroll
    for (int i = 0; i < 18; ++i)
      bv[i] = *(const bf16x8*)(bp + i * 32);
  }

  // prologue: prefetch tile-0 offsets
  float dy = 0.f, dx = 0.f;
  if (pthr) {
    const int rem = rem_base + px0;
    dy = offb[(size_t)(2 * tap0) * HW + rem];
    dx = offb[(size_t)(2 * tap0 + 1) * HW + rem];
  }

  int prev_rem0 = 0;

  #pragma unroll 1
  for (int t = 0; t < TPB; ++t) {
    const int rem0 = rem_base + t * PXB;
    const int pb = t & 1;

    // ---- A: params(t) from prefetched offset regs ----
    if (pthr) {
      const int rem = rem0 + px0;
      const int y = rem >> 7;
      const int x = rem & 127;
      const float fy = floorf(dy);
      const float fx = floorf(dx);
      const float ly = dy - fy;
      const float lx = dx - fx;
      const int y0 = y - 1 + (tap0 / 3) + (int)fy;
      const int x0 = x - 1 + (tap0 % 3) + (int)fx;
      const int y1 = y0 + 1, x1 = x0 + 1;
      const bool vy0 = (unsigned)y0 < (unsigned)HH;
      const bool vy1 = (unsigned)y1 < (unsigned)HH;
      const bool vx0 = (unsigned)x0 < (unsigned)WW;
      const bool vx1 = (unsigned)x1 < (unsigned)WW;
      const int cy0 = min(max(y0, 0), HH - 1);
      const int cy1 = min(max(y1, 0), HH - 1);
      const int cx0 = min(max(x0, 0), WW - 1);
      const int cx1 = min(max(x1, 0), WW - 1);
      const float omly = 1.f - ly, omlx = 1.f - lx;
      f32x4 w4;
      w4[0] = (vy0 && vx0) ? omly * omlx : 0.f;
      w4[1] = (vy0 && vx1) ? omly * lx : 0.f;
      w4[2] = (vy1 && vx0) ? ly * omlx : 0.f;
      w4[3] = (vy1 && vx1) ? ly * lx : 0.f;
      const unsigned i00 = (unsigned)(cy0 * WW + cx0);
      const unsigned i01 = (unsigned)(cy0 * WW + cx1);
      const unsigned i10 = (unsigned)(cy1 * WW + cx0);
      const unsigned i11 = (unsigned)(cy1 * WW + cx1);
      pw[pb][tid] = w4;
      pidx[pb][tid] = make_uint2(i00 | (i01 << 16), i10 | (i11 << 16));
    }
    __syncthreads();   // B2: params(t) visible; s(t-1) writes visible

    // ---- C: prefetch offsets(t+1), in flight across M/E ----
    if (t + 1 < TPB && pthr) {
      const int rem = rem0 + PXB + px0;
      dy = offb[(size_t)(2 * tap0) * HW + rem];
      dx = offb[(size_t)(2 * tap0 + 1) * HW + rem];
    }

    // ---- D: issue 36 corner gathers for tile t ----
    const int px = wave * 4 + g;
    uint2 id[9];
    #pragma unroll
    for (int k = 0; k < 9; ++k) id[k] = pidx[pb][k * 16 + px];
    u16x4 V00[9], V01[9], V10[9], V11[9];
    #pragma unroll
    for (int k = 0; k < 9; ++k) {
      V00[k] = *(const u16x4*)(xli + (size_t)(id[k].x & 0xffffu) * CIN);
      V01[k] = *(const u16x4*)(xli + (size_t)(id[k].x >> 16) * CIN);
      V10[k] = *(const u16x4*)(xli + (size_t)(id[k].y & 0xffffu) * CIN);
      V11[k] = *(const u16x4*)(xli + (size_t)(id[k].y >> 16) * CIN);
    }
    __builtin_amdgcn_sched_barrier(0);

    // ---- M: MFMA(t-1) — pure LDS+reg, hides gather latency ----
    if (t > 0) {
      f32x4 acc = {0.f, 0.f, 0.f, 0.f};
      const unsigned short* ap = &s[li][g * 8];
      #pragma unroll
      for (int i = 0; i < 18; ++i) {
        bf16x8 av = *(const bf16x8*)(ap + i * 32);
        acc = __builtin_amdgcn_mfma_f32_16x16x32_bf16(av, bv[i], acc, 0, 0, 0);
      }
      const int oc = wave * 16 + li;
      float* ob = out + ((size_t)n * COUT + oc) * HW + prev_rem0 + g * 4;
      *(f32x4*)ob = acc;
    }
    __builtin_amdgcn_sched_barrier(0);
    __syncthreads();   // B3: all MFMA(t-1) s-reads done before overwrite

    // ---- E: blend + write s(t) ----
    #pragma unroll
    for (int k = 0; k < 9; ++k) {
      const f32x4 w = pw[pb][k * 16 + px];
      float a0 = 0.f, a1 = 0.f, a2 = 0.f, a3 = 0.f;
      #define CORNER(v, wc)                                        \
        a0 = fmaf(bits_f32((unsigned)(v)[0] << 16), (wc), a0);     \
        a1 = fmaf(bits_f32((unsigned)(v)[1] << 16), (wc), a1);     \
        a2 = fmaf(bits_f32((unsigned)(v)[2] << 16), (wc), a2);     \
        a3 = fmaf(bits_f32((unsigned)(v)[3] << 16), (wc), a3);
      CORNER(V00[k], w[0]);
      CORNER(V01[k], w[1]);
      CORNER(V10[k], w[2]);
      CORNER(V11[k], w[3]);
      #undef CORNER
      unsigned r01, r23;
      asm("v_cvt_pk_bf16_f32 %0, %1, %2" : "=v"(r01) : "v"(a0), "v"(a1));
      asm("v_cvt_pk_bf16_f32 %0, %1, %2" : "=v"(r23) : "v"(a2), "v"(a3));
      *(uint2*)&s[px][k * 64 + li * 4] = make_uint2(r01, r23);
    }
    prev_rem0 = rem0;
  }

  // ---- epilogue: MFMA(TPB-1) ----
  __syncthreads();
  {
    f32x4 acc = {0.f, 0.f, 0.f, 0.f};
    const unsigned short* ap = &s[li][g * 8];
    #pragma unroll
    for (int i = 0; i < 18; ++i) {
      bf16x8 av = *(const bf16x8*)(ap + i * 32);
      acc = __builtin_amdgcn_mfma_f32_16x16x32_bf16(av, bv[i], acc, 0, 0, 0);
    }
    const int oc = wave * 16 + li;
    float* ob = out + ((size_t)n * COUT + oc) * HW + prev_rem0 + g * 4;
    *(f32x4*)ob = acc;
  }
}

// ---------------- fp32 fallback (ws too small) --------------------------
__global__ __launch_bounds__(256) void deform_fallback(
    const float* __restrict__ xsrc, const float* __restrict__ offset,
    const float* __restrict__ wsrc, float* __restrict__ out) {
  __shared__ float s[16][576];
  const int wave = threadIdx.x >> 6;
  const int lane = threadIdx.x & 63;
  const int p0 = blockIdx.x * 16;
  for (int i = 0; i < 4; ++i) {
    const int p = p0 + wave * 4 + i;
    const int n = p >> 14;
    const int rem = p & 16383;
    const int y = rem >> 7;
    const int x = rem & 127;
    const float* off = offset + (size_t)n * 18 * HW + rem;
    const float* xb = xsrc + (size_t)n * CIN * HW;
    #pragma unroll
    for (int k = 0; k < 9; ++k) {
      const float dy = off[(size_t)(2 * k) * HW];
      const float dx = off[(size_t)(2 * k + 1) * HW];
      const float py = (float)(y - 1 + k / 3) + dy;
      const float px = (float)(x - 1 + k % 3) + dx;
      const float y0f = floorf(py), x0f = floorf(px);
      const float ly = py - y0f, lx = px - x0f;
      const int y0 = (int)y0f, x0 = (int)x0f;
      const int y1 = y0 + 1, x1 = x0 + 1;
      const bool vy0 = (y0 >= 0) && (y0 < HH), vy1 = (y1 >= 0) && (y1 < HH);
      const bool vx0 = (x0 >= 0) && (x0 < WW), vx1 = (x1 >= 0) && (x1 < WW);
      const int cy0 = min(max(y0, 0), HH - 1), cy1 = min(max(y1, 0), HH - 1);
      const int cx0 = min(max(x0, 0), WW - 1), cx1 = min(max(x1, 0), WW - 1);
      const float v00 = (vy0 && vx0) ? xb[(size_t)lane * HW + cy0 * WW + cx0] : 0.f;
      const float v01 = (vy0 && vx1) ? xb[(size_t)lane * HW + cy0 * WW + cx1] : 0.f;
      const float v10 = (vy1 && vx0) ? xb[(size_t)lane * HW + cy1 * WW + cx0] : 0.f;
      const float v11 = (vy1 && vx1) ? xb[(size_t)lane * HW + cy1 * WW + cx1] : 0.f;
      s[wave * 4 + i][k * 64 + lane] =
          v00 * (1.f - ly) * (1.f - lx) + v01 * (1.f - ly) * lx +
          v10 * ly * (1.f - lx) + v11 * ly * lx;
    }
  }
  __syncthreads();
  float a0 = 0.f, a1 = 0.f, a2 = 0.f, a3 = 0.f;
  const int pb = wave * 4;
  for (int t = 0; t < 576; ++t) {
    const int c = t & 63;
    const int k = t >> 6;
    const float wv = wsrc[((size_t)lane * 64 + c) * 9 + k];
    a0 += s[pb + 0][t] * wv;
    a1 += s[pb + 1][t] * wv;
    a2 += s[pb + 2][t] * wv;
    a3 += s[pb + 3][t] * wv;
  }
  const float acc[4] = {a0, a1, a2, a3};
  for (int i = 0; i < 4; ++i) {
    const int p = p0 + pb + i;
    const int n = p >> 14;
    const int rem = p & 16383;
    out[((size_t)n * COUT + lane) * HW + rem] = acc[i];
  }
}

extern "C" void kernel_launch(void* const* d_in, const int* in_sizes, int n_in,
                              void* d_out, int out_size, void* d_ws,
                              size_t ws_size, hipStream_t stream) {
  const float* x = (const float*)d_in[0];
  const float* offset = (const float*)d_in[1];
  const float* weight = (const float*)d_in[2];
  float* out = (float*)d_out;

  const size_t xt_elems = (size_t)NB * HW * CIN;       // bf16
  const size_t wt_elems = (size_t)64 * 576;            // bf16
  const size_t need = (xt_elems + wt_elems) * sizeof(short);

  if (ws_size >= need) {
    unsigned short* xtp = (unsigned short*)d_ws;
    unsigned short* wtp = xtp + xt_elems;
    prep_kernel<<<1024 + 144, 256, 0, stream>>>(x, weight, xtp, wtp);
    deform_mfma<<<NB * HW / (PXB * TPB), 256, 0, stream>>>(xtp, offset, wtp, out);
  } else {
    deform_fallback<<<NB * HW / 16, 256, 0, stream>>>(x, offset, weight, out);
  }
}